// Round 1
// baseline (1093.362 us; speedup 1.0000x reference)
//
#include <hip/hip_runtime.h>
#include <hip/hip_bf16.h>
#include <stdint.h>

typedef __attribute__((ext_vector_type(4))) float f32x4;
typedef __attribute__((ext_vector_type(8))) short s16x8;
typedef __attribute__((ext_vector_type(4))) unsigned short u16x4;

#define EPSBN 1e-5f

__device__ __forceinline__ float bf2f(unsigned short u) {
  union { unsigned int i; float f; } w; w.i = ((unsigned int)u) << 16; return w.f;
}
__device__ __forceinline__ unsigned short f2bf(float f) {
  __hip_bfloat16 h = __float2bfloat16(f);   // RNE
  unsigned short u; __builtin_memcpy(&u, &h, 2); return u;
}
// async global->LDS, 16B. LDS dest must be wave-uniform base (+lane*16 implicit).
__device__ __forceinline__ void gld_lds16(const unsigned short* g, unsigned short* l) {
  __builtin_amdgcn_global_load_lds(
      (__attribute__((address_space(1))) void*)(g),
      (__attribute__((address_space(3))) void*)(l), 16, 0, 0);
}

// ---------------- graph prep ----------------
__global__ void k_init_deg(unsigned* deg, int n) {
  int i = blockIdx.x * 256 + threadIdx.x;
  if (i < n) deg[i] = 1u;               // self-loop
}
__global__ void k_count(const int* __restrict__ dst, unsigned* __restrict__ deg, int E) {
  int i = blockIdx.x * 256 + threadIdx.x;
  if (i < E) atomicAdd(&deg[dst[i]], 1u);
}
__global__ void k_dinv(const unsigned* __restrict__ deg, float* __restrict__ dinv, int n) {
  int i = blockIdx.x * 256 + threadIdx.x;
  if (i < n) dinv[i] = rsqrtf((float)deg[i]);
}
__global__ void k_bsum(const unsigned* __restrict__ deg, unsigned* __restrict__ bsum, int n) {
  __shared__ unsigned s[256];
  int t = threadIdx.x, i = blockIdx.x * 256 + t;
  s[t] = (i < n) ? deg[i] : 0u;
  __syncthreads();
  for (int st = 128; st > 0; st >>= 1) {
    if (t < st) s[t] += s[t + st];
    __syncthreads();
  }
  if (t == 0) bsum[blockIdx.x] = s[0];
}
__global__ void k_scan_top(const unsigned* __restrict__ bsum, unsigned* __restrict__ bpre,
                           int nb, unsigned* __restrict__ offs, int n) {
  __shared__ unsigned s[256];
  int t = threadIdx.x;
  unsigned v = (t < nb) ? bsum[t] : 0u;
  s[t] = v; __syncthreads();
  for (int d = 1; d < 256; d <<= 1) {
    unsigned a = (t >= d) ? s[t - d] : 0u;
    __syncthreads();
    s[t] += a;
    __syncthreads();
  }
  bpre[t] = s[t] - v;                    // exclusive
  if (t == 255) offs[n] = s[255];        // total = E + n
}
__global__ void k_scan_fin(const unsigned* __restrict__ deg, const unsigned* __restrict__ bpre,
                           unsigned* __restrict__ offs, unsigned* __restrict__ cur, int n) {
  __shared__ unsigned s[256];
  int t = threadIdx.x, i = blockIdx.x * 256 + t;
  unsigned v = (i < n) ? deg[i] : 0u;
  s[t] = v; __syncthreads();
  for (int d = 1; d < 256; d <<= 1) {
    unsigned a = (t >= d) ? s[t - d] : 0u;
    __syncthreads();
    s[t] += a;
    __syncthreads();
  }
  if (i < n) {
    unsigned o = bpre[blockIdx.x] + s[t] - v;
    offs[i] = o; cur[i] = o;
  }
}
__global__ void k_fill(const int* __restrict__ src, const int* __restrict__ dst,
                       unsigned* __restrict__ cur, int* __restrict__ adj, int E, int n) {
  int i = blockIdx.x * 256 + threadIdx.x;
  int s, d;
  if (i < E)          { s = src[i]; d = dst[i]; }
  else if (i < E + n) { s = d = i - E; }        // self-loop
  else return;
  unsigned p = atomicAdd(&cur[d], 1u);
  adj[p] = s;
}
// W [K][N] fp32 -> Wt [Npad][K] bf16 (rows >= N zero)
__global__ void k_wt(const float* __restrict__ W, unsigned short* __restrict__ Wt,
                     int K, int N, int Npad) {
  int idx = blockIdx.x * 256 + threadIdx.x;
  if (idx >= Npad * K) return;
  int nn = idx / K, k = idx - nn * K;
  float v = (nn < N) ? W[(size_t)k * N + nn] : 0.f;
  Wt[idx] = f2bf(v);
}

// ---------------- GEMM: C[M,N] = A[M,K] * Bt[N,K]^T, bf16 MFMA ----------------
#define BM 128
#define BN 128
#define BK 64

template<int CONVA>
__global__ __launch_bounds__(256, 2) void k_gemm(
    const void* __restrict__ Aall, const unsigned short* __restrict__ Bt,
    unsigned short* __restrict__ Cout, int M, int N, int K, int MT, int NT)
{
  __shared__ __align__(16) unsigned short As[BM * BK];
  __shared__ __align__(16) unsigned short Bs[BN * BK];

  // XCD pairing: all NT col-tiles of an M-tile share d%8 (same XCD, 8 apart)
  int d = blockIdx.x;
  int xc = d & 7, sb = d >> 3;
  int nt = sb % NT, mt = (sb / NT) * 8 + xc;
  if (mt >= MT) return;
  int m0 = mt * BM, n0 = nt * BN;

  int tid = threadIdx.x, lane = tid & 63, wave = tid >> 6;
  int wm = wave >> 1, wn = wave & 1;
  int l15 = lane & 15, l4 = lane >> 4;

  f32x4 acc[4][4];
#pragma unroll
  for (int i = 0; i < 4; ++i)
#pragma unroll
    for (int j = 0; j < 4; ++j) acc[i][j] = 0.f;

  // staging geometry: 4 chunks of 16B per thread per matrix
  int srow[4], scg[4], sci[4];
#pragma unroll
  for (int i = 0; i < 4; ++i) {
    int ci = (wave + 4 * i) * 64 + lane;
    sci[i] = ci;
    srow[i] = ci >> 3;                         // 8 chunks per 128B row
    scg[i] = (ci & 7) ^ (srow[i] & 7);         // pre-swizzled source chunk
  }
  const float* Af = (const float*)Aall;
  const unsigned short* Au = (const unsigned short*)Aall;

  int nk = K / BK;
  for (int kt = 0; kt < nk; ++kt) {
    __syncthreads();
#pragma unroll
    for (int i = 0; i < 4; ++i) {
      int gr = m0 + srow[i]; gr = gr < M ? gr : M - 1;
      if (CONVA) {
        const float* p = Af + (size_t)gr * K + kt * BK + scg[i] * 8;
        f32x4 f0 = *(const f32x4*)p;
        f32x4 f1 = *(const f32x4*)(p + 4);
        s16x8 pk;
        pk[0] = (short)f2bf(f0[0]); pk[1] = (short)f2bf(f0[1]);
        pk[2] = (short)f2bf(f0[2]); pk[3] = (short)f2bf(f0[3]);
        pk[4] = (short)f2bf(f1[0]); pk[5] = (short)f2bf(f1[1]);
        pk[6] = (short)f2bf(f1[2]); pk[7] = (short)f2bf(f1[3]);
        *(s16x8*)(As + sci[i] * 8) = pk;
      } else {
        gld_lds16(Au + (size_t)gr * K + kt * BK + scg[i] * 8, As + (wave + 4 * i) * 512);
      }
    }
#pragma unroll
    for (int i = 0; i < 4; ++i) {
      int gn = n0 + srow[i];
      gld_lds16(Bt + (size_t)gn * K + kt * BK + scg[i] * 8, Bs + (wave + 4 * i) * 512);
    }
    __syncthreads();   // compiler drains vmcnt/lgkmcnt before s_barrier

#pragma unroll
    for (int ks = 0; ks < 2; ++ks) {
      s16x8 af[4], bf[4];
#pragma unroll
      for (int f = 0; f < 4; ++f) {
        int r = wm * 64 + f * 16 + l15;
        int ca = (ks * 4 + l4) ^ (r & 7);
        af[f] = *(const s16x8*)(As + r * 64 + ca * 8);
        int nloc = wn * 64 + f * 16 + l15;
        int cb = (ks * 4 + l4) ^ (nloc & 7);
        bf[f] = *(const s16x8*)(Bs + nloc * 64 + cb * 8);
      }
#pragma unroll
      for (int fm = 0; fm < 4; ++fm)
#pragma unroll
        for (int fn = 0; fn < 4; ++fn)
          acc[fm][fn] = __builtin_amdgcn_mfma_f32_16x16x32_bf16(af[fm], bf[fn], acc[fm][fn], 0, 0, 0);
    }
  }

  // epilogue: C/D layout col=lane&15, row=(lane>>4)*4+reg
#pragma unroll
  for (int fm = 0; fm < 4; ++fm) {
#pragma unroll
    for (int fn = 0; fn < 4; ++fn) {
#pragma unroll
      for (int r = 0; r < 4; ++r) {
        int row = m0 + wm * 64 + fm * 16 + l4 * 4 + r;
        int col = n0 + wn * 64 + fn * 16 + l15;
        if (row < M && col < N)
          Cout[(size_t)row * N + col] = f2bf(acc[fm][fn][r]);
      }
    }
  }
}

// ---------------- aggregation: out[v] = sum_{e in CSR[v]} h[src]*dinv[src]*dinv[v] (+b, BN, ReLU) ----
template<int C, int BNRELU, int OUTBF>
__global__ __launch_bounds__(256) void k_agg(
    const unsigned short* __restrict__ h, const int* __restrict__ adj,
    const unsigned* __restrict__ offs, const float* __restrict__ dinv,
    const float* __restrict__ bias, const float* __restrict__ gam,
    const float* __restrict__ bet, const float* __restrict__ mea,
    const float* __restrict__ var, void* __restrict__ outp, int nN)
{
  int wave = threadIdx.x >> 6, lane = threadIdx.x & 63;
  int v = blockIdx.x * 4 + wave;
  if (v >= nN) return;
  unsigned beg = offs[v], end = offs[v + 1];
  float dv = dinv[v];
  int ch0 = lane * 4;
  float a0 = 0, a1 = 0, a2 = 0, a3 = 0;
  float c0 = 0, c1 = 0, c2 = 0, c3 = 0;
  const bool has1 = (C > 256) && (ch0 + 256 < C);
  for (unsigned e = beg; e < end; ++e) {
    int s = adj[e];
    float w = dinv[s] * dv;
    u16x4 q = *(const u16x4*)(h + (size_t)s * C + ch0);
    a0 += bf2f(q[0]) * w; a1 += bf2f(q[1]) * w;
    a2 += bf2f(q[2]) * w; a3 += bf2f(q[3]) * w;
    if (has1) {
      u16x4 r = *(const u16x4*)(h + (size_t)s * C + 256 + ch0);
      c0 += bf2f(r[0]) * w; c1 += bf2f(r[1]) * w;
      c2 += bf2f(r[2]) * w; c3 += bf2f(r[3]) * w;
    }
  }
  float va[4] = {a0, a1, a2, a3};
#pragma unroll
  for (int j = 0; j < 4; ++j) {
    int ch = ch0 + j;
    float val = va[j] + bias[ch];
    if (BNRELU) {
      val = (val - mea[ch]) * rsqrtf(var[ch] + EPSBN) * gam[ch] + bet[ch];
      val = fmaxf(val, 0.f);
    }
    if (OUTBF) ((unsigned short*)outp)[(size_t)v * C + ch] = f2bf(val);
    else       ((float*)outp)[(size_t)v * C + ch] = val;
  }
  if (C > 256 && has1) {
    float vb[4] = {c0, c1, c2, c3};
#pragma unroll
    for (int j = 0; j < 4; ++j) {
      int ch = 256 + ch0 + j;
      float val = vb[j] + bias[ch];
      if (BNRELU) {
        val = (val - mea[ch]) * rsqrtf(var[ch] + EPSBN) * gam[ch] + bet[ch];
        val = fmaxf(val, 0.f);
      }
      if (OUTBF) ((unsigned short*)outp)[(size_t)v * C + ch] = f2bf(val);
      else       ((float*)outp)[(size_t)v * C + ch] = val;
    }
  }
}

// ---------------- launch ----------------
extern "C" void kernel_launch(void* const* d_in, const int* in_sizes, int n_in,
                              void* d_out, int out_size, void* d_ws, size_t ws_size,
                              hipStream_t stream) {
  const float* x   = (const float*)d_in[0];
  const int*   ei  = (const int*)d_in[1];
  const float* W1  = (const float*)d_in[2];
  const float* b1  = (const float*)d_in[3];
  const float* g1  = (const float*)d_in[4];
  const float* be1 = (const float*)d_in[5];
  const float* m1  = (const float*)d_in[6];
  const float* v1  = (const float*)d_in[7];
  const float* W2  = (const float*)d_in[8];
  const float* b2  = (const float*)d_in[9];
  const float* g2  = (const float*)d_in[10];
  const float* be2 = (const float*)d_in[11];
  const float* m2  = (const float*)d_in[12];
  const float* v2  = (const float*)d_in[13];
  const float* W3  = (const float*)d_in[14];
  const float* b3  = (const float*)d_in[15];

  const int IN = 1280, H = 256, OUT = 500, OUTP = 512;
  int E  = in_sizes[1] / 2;
  int nN = in_sizes[0] / IN;
  const int* srcI = ei;
  const int* dstI = ei + E;

  char* p = (char*)d_ws;
  auto carve = [&](size_t bytes) { char* r = p; p += (bytes + 511) & ~(size_t)511; return r; };
  unsigned short* Wt1 = (unsigned short*)carve((size_t)H * IN * 2);
  unsigned short* Wt2 = (unsigned short*)carve((size_t)H * H * 2);
  unsigned short* Wt3 = (unsigned short*)carve((size_t)OUTP * H * 2);
  unsigned* deg  = (unsigned*)carve((size_t)nN * 4);
  float*    dinv = (float*)carve((size_t)nN * 4);
  unsigned* offs = (unsigned*)carve((size_t)(nN + 1) * 4);
  unsigned* cur  = (unsigned*)carve((size_t)nN * 4);
  unsigned* bsum = (unsigned*)carve(256 * 4);
  unsigned* bpre = (unsigned*)carve(256 * 4);
  int*      adj  = (int*)carve((size_t)(E + nN) * 4);
  unsigned short* act  = (unsigned short*)carve((size_t)nN * H * 2);
  unsigned short* gout = (unsigned short*)carve((size_t)nN * OUT * 2);

  int NB = (nN + 255) / 256;
  k_init_deg<<<NB, 256, 0, stream>>>(deg, nN);
  k_count<<<(E + 255) / 256, 256, 0, stream>>>(dstI, deg, E);
  k_dinv<<<NB, 256, 0, stream>>>(deg, dinv, nN);
  k_bsum<<<NB, 256, 0, stream>>>(deg, bsum, nN);
  k_scan_top<<<1, 256, 0, stream>>>(bsum, bpre, NB, offs, nN);
  k_scan_fin<<<NB, 256, 0, stream>>>(deg, bpre, offs, cur, nN);
  k_fill<<<(E + nN + 255) / 256, 256, 0, stream>>>(srcI, dstI, cur, adj, E, nN);

  k_wt<<<(H * IN + 255) / 256, 256, 0, stream>>>(W1, Wt1, IN, H, H);
  k_wt<<<(H * H + 255) / 256, 256, 0, stream>>>(W2, Wt2, H, H, H);
  k_wt<<<(OUTP * H + 255) / 256, 256, 0, stream>>>(W3, Wt3, H, OUT, OUTP);

  int MT = (nN + BM - 1) / BM;          // 391
  int mg = (MT + 7) / 8;                // 49
  int nAgg = (nN + 3) / 4;

  // layer 1
  k_gemm<1><<<mg * 8 * 2, 256, 0, stream>>>(x, Wt1, gout, nN, H, IN, MT, 2);
  k_agg<256, 1, 1><<<nAgg, 256, 0, stream>>>(gout, adj, offs, dinv, b1, g1, be1, m1, v1, act, nN);
  // layer 2
  k_gemm<0><<<mg * 8 * 2, 256, 0, stream>>>(act, Wt2, gout, nN, H, H, MT, 2);
  k_agg<256, 1, 1><<<nAgg, 256, 0, stream>>>(gout, adj, offs, dinv, b2, g2, be2, m2, v2, act, nN);
  // layer 3
  k_gemm<0><<<mg * 8 * 4, 256, 0, stream>>>(act, Wt3, gout, nN, OUT, H, MT, 4);
  k_agg<500, 0, 0><<<nAgg, 256, 0, stream>>>(gout, adj, offs, dinv, b3, nullptr, nullptr, nullptr, nullptr, d_out, nN);
}

// Round 2
// 1020.265 us; speedup vs baseline: 1.0716x; 1.0716x over previous
//
#include <hip/hip_runtime.h>
#include <hip/hip_bf16.h>
#include <stdint.h>

typedef __attribute__((ext_vector_type(4))) float f32x4;
typedef __attribute__((ext_vector_type(8))) short s16x8;
typedef __attribute__((ext_vector_type(4))) unsigned short u16x4;

#define EPSBN 1e-5f

__device__ __forceinline__ float bf2f(unsigned short u) {
  union { unsigned int i; float f; } w; w.i = ((unsigned int)u) << 16; return w.f;
}
__device__ __forceinline__ unsigned short f2bf(float f) {
  __hip_bfloat16 h = __float2bfloat16(f);   // RNE
  unsigned short u; __builtin_memcpy(&u, &h, 2); return u;
}
__device__ __forceinline__ void gld_lds16(const unsigned short* g, unsigned short* l) {
  __builtin_amdgcn_global_load_lds(
      (__attribute__((address_space(1))) void*)(g),
      (__attribute__((address_space(3))) void*)(l), 16, 0, 0);
}

// ---------------- graph prep ----------------
__global__ void k_init_deg(unsigned* deg, int n) {
  int i = blockIdx.x * 256 + threadIdx.x;
  if (i < n) deg[i] = 1u;               // self-loop
}
__global__ void k_count(const int* __restrict__ dst, unsigned* __restrict__ deg, int E) {
  int i = blockIdx.x * 256 + threadIdx.x;
  if (i < E) atomicAdd(&deg[dst[i]], 1u);
}
__global__ void k_dinv(const unsigned* __restrict__ deg, float* __restrict__ dinv, int n) {
  int i = blockIdx.x * 256 + threadIdx.x;
  if (i < n) dinv[i] = rsqrtf((float)deg[i]);
}
__global__ void k_bsum(const unsigned* __restrict__ deg, unsigned* __restrict__ bsum, int n) {
  __shared__ unsigned s[256];
  int t = threadIdx.x, i = blockIdx.x * 256 + t;
  s[t] = (i < n) ? deg[i] : 0u;
  __syncthreads();
  for (int st = 128; st > 0; st >>= 1) {
    if (t < st) s[t] += s[t + st];
    __syncthreads();
  }
  if (t == 0) bsum[blockIdx.x] = s[0];
}
__global__ void k_scan_top(const unsigned* __restrict__ bsum, unsigned* __restrict__ bpre,
                           int nb, unsigned* __restrict__ offs, int n) {
  __shared__ unsigned s[256];
  int t = threadIdx.x;
  unsigned v = (t < nb) ? bsum[t] : 0u;
  s[t] = v; __syncthreads();
  for (int d = 1; d < 256; d <<= 1) {
    unsigned a = (t >= d) ? s[t - d] : 0u;
    __syncthreads();
    s[t] += a;
    __syncthreads();
  }
  bpre[t] = s[t] - v;                    // exclusive
  if (t == 255) offs[n] = s[255];        // total = E + n
}
__global__ void k_scan_fin(const unsigned* __restrict__ deg, const unsigned* __restrict__ bpre,
                           unsigned* __restrict__ offs, unsigned* __restrict__ cur, int n) {
  __shared__ unsigned s[256];
  int t = threadIdx.x, i = blockIdx.x * 256 + t;
  unsigned v = (i < n) ? deg[i] : 0u;
  s[t] = v; __syncthreads();
  for (int d = 1; d < 256; d <<= 1) {
    unsigned a = (t >= d) ? s[t - d] : 0u;
    __syncthreads();
    s[t] += a;
    __syncthreads();
  }
  if (i < n) {
    unsigned o = bpre[blockIdx.x] + s[t] - v;
    offs[i] = o; cur[i] = o;
  }
}
__global__ void k_fill(const int* __restrict__ src, const int* __restrict__ dst,
                       unsigned* __restrict__ cur, int* __restrict__ adj, int E, int n) {
  int i = blockIdx.x * 256 + threadIdx.x;
  int s, d;
  if (i < E)          { s = src[i]; d = dst[i]; }
  else if (i < E + n) { s = d = i - E; }        // self-loop
  else return;
  unsigned p = atomicAdd(&cur[d], 1u);
  adj[p] = s;
}
// per-dst insertion sort of adj segments (src-ascending) for L2 sweep locality
#define SORT_CAP 96
__global__ __launch_bounds__(256) void k_sort(const unsigned* __restrict__ offs,
                                              int* __restrict__ adj, int nN) {
  __shared__ int buf[SORT_CAP * 256];    // 96 KB, column-per-thread (stride 256)
  int t = threadIdx.x;
  int v = blockIdx.x * 256 + t;
  if (v >= nN) return;
  unsigned b = offs[v], e = offs[v + 1];
  int len = (int)(e - b);
  if (len > SORT_CAP) return;            // pathological degree: leave unsorted (still correct)
  for (int i = 0; i < len; ++i) buf[i * 256 + t] = adj[b + i];
  for (int i = 1; i < len; ++i) {
    int key = buf[i * 256 + t];
    int j = i - 1;
    while (j >= 0 && buf[j * 256 + t] > key) {
      buf[(j + 1) * 256 + t] = buf[j * 256 + t];
      --j;
    }
    buf[(j + 1) * 256 + t] = key;
  }
  for (int i = 0; i < len; ++i) adj[b + i] = buf[i * 256 + t];
}
// W [K][N] fp32 -> Wt [Npad][K] bf16 (rows >= N zero)
__global__ void k_wt(const float* __restrict__ W, unsigned short* __restrict__ Wt,
                     int K, int N, int Npad) {
  int idx = blockIdx.x * 256 + threadIdx.x;
  if (idx >= Npad * K) return;
  int nn = idx / K, k = idx - nn * K;
  float v = (nn < N) ? W[(size_t)k * N + nn] : 0.f;
  Wt[idx] = f2bf(v);
}

// ---------------- GEMM: C[M,N] = A[M,K] * Bt[N,K]^T, bf16 MFMA ----------------
#define BM 128
#define BN 128
#define BK 64

template<int CONVA, int OUTF32>
__global__ __launch_bounds__(256, 2) void k_gemm(
    const void* __restrict__ Aall, const unsigned short* __restrict__ Bt,
    void* __restrict__ Coutv, const float* __restrict__ bias,
    int M, int N, int K, int MT, int NT)
{
  __shared__ __align__(16) unsigned short As[BM * BK];
  __shared__ __align__(16) unsigned short Bs[BN * BK];

  // XCD pairing: all NT col-tiles of an M-tile share d%8 (same XCD, 8 apart)
  int d = blockIdx.x;
  int xc = d & 7, sb = d >> 3;
  int nt = sb % NT, mt = (sb / NT) * 8 + xc;
  if (mt >= MT) return;
  int m0 = mt * BM, n0 = nt * BN;

  int tid = threadIdx.x, lane = tid & 63, wave = tid >> 6;
  int wm = wave >> 1, wn = wave & 1;
  int l15 = lane & 15, l4 = lane >> 4;

  f32x4 acc[4][4];
#pragma unroll
  for (int i = 0; i < 4; ++i)
#pragma unroll
    for (int j = 0; j < 4; ++j) acc[i][j] = 0.f;

  int srow[4], scg[4], sci[4];
#pragma unroll
  for (int i = 0; i < 4; ++i) {
    int ci = (wave + 4 * i) * 64 + lane;
    sci[i] = ci;
    srow[i] = ci >> 3;                         // 8 chunks per 128B row
    scg[i] = (ci & 7) ^ (srow[i] & 7);         // pre-swizzled source chunk
  }
  const float* Af = (const float*)Aall;
  const unsigned short* Au = (const unsigned short*)Aall;

  int nk = K / BK;
  for (int kt = 0; kt < nk; ++kt) {
    __syncthreads();
#pragma unroll
    for (int i = 0; i < 4; ++i) {
      int gr = m0 + srow[i]; gr = gr < M ? gr : M - 1;
      if (CONVA) {
        const float* p = Af + (size_t)gr * K + kt * BK + scg[i] * 8;
        f32x4 f0 = *(const f32x4*)p;
        f32x4 f1 = *(const f32x4*)(p + 4);
        s16x8 pk;
        pk[0] = (short)f2bf(f0[0]); pk[1] = (short)f2bf(f0[1]);
        pk[2] = (short)f2bf(f0[2]); pk[3] = (short)f2bf(f0[3]);
        pk[4] = (short)f2bf(f1[0]); pk[5] = (short)f2bf(f1[1]);
        pk[6] = (short)f2bf(f1[2]); pk[7] = (short)f2bf(f1[3]);
        *(s16x8*)(As + sci[i] * 8) = pk;
      } else {
        gld_lds16(Au + (size_t)gr * K + kt * BK + scg[i] * 8, As + (wave + 4 * i) * 512);
      }
    }
#pragma unroll
    for (int i = 0; i < 4; ++i) {
      int gn = n0 + srow[i];
      gld_lds16(Bt + (size_t)gn * K + kt * BK + scg[i] * 8, Bs + (wave + 4 * i) * 512);
    }
    __syncthreads();

#pragma unroll
    for (int ks = 0; ks < 2; ++ks) {
      s16x8 af[4], bf[4];
#pragma unroll
      for (int f = 0; f < 4; ++f) {
        int r = wm * 64 + f * 16 + l15;
        int ca = (ks * 4 + l4) ^ (r & 7);
        af[f] = *(const s16x8*)(As + r * 64 + ca * 8);
        int nloc = wn * 64 + f * 16 + l15;
        int cb = (ks * 4 + l4) ^ (nloc & 7);
        bf[f] = *(const s16x8*)(Bs + nloc * 64 + cb * 8);
      }
#pragma unroll
      for (int fm = 0; fm < 4; ++fm)
#pragma unroll
        for (int fn = 0; fn < 4; ++fn)
          acc[fm][fn] = __builtin_amdgcn_mfma_f32_16x16x32_bf16(af[fm], bf[fn], acc[fm][fn], 0, 0, 0);
    }
  }

  // epilogue: C/D layout col=lane&15, row=(lane>>4)*4+reg
#pragma unroll
  for (int fm = 0; fm < 4; ++fm) {
#pragma unroll
    for (int fn = 0; fn < 4; ++fn) {
#pragma unroll
      for (int r = 0; r < 4; ++r) {
        int row = m0 + wm * 64 + fm * 16 + l4 * 4 + r;
        int col = n0 + wn * 64 + fn * 16 + l15;
        if (row < M && col < N) {
          if (OUTF32)
            ((float*)Coutv)[(size_t)row * N + col] = acc[fm][fn][r] + bias[col];
          else
            ((unsigned short*)Coutv)[(size_t)row * N + col] = f2bf(acc[fm][fn][r]);
        }
      }
    }
  }
}

// -------- aggregation (C=256): out[v] = sum_e h[src]*dinv[src]*dinv[v] (+bias,BN,ReLU) --------
template<int BNRELU, int BIAS>
__global__ __launch_bounds__(256) void k_agg(
    const unsigned short* __restrict__ h, const int* __restrict__ adj,
    const unsigned* __restrict__ offs, const float* __restrict__ dinv,
    const float* __restrict__ bias, const float* __restrict__ gam,
    const float* __restrict__ bet, const float* __restrict__ mea,
    const float* __restrict__ var, unsigned short* __restrict__ outp, int nN)
{
  const int C = 256;
  int wave = threadIdx.x >> 6, lane = threadIdx.x & 63;
  int v = blockIdx.x * 4 + wave;
  if (v >= nN) return;
  unsigned beg = offs[v], end = offs[v + 1];
  float dv = dinv[v];
  int ch0 = lane * 4;
  float a0 = 0, a1 = 0, a2 = 0, a3 = 0;
  int s = adj[beg];                       // deg >= 1 (self-loop)
  for (unsigned e = beg; e < end; ++e) {
    int sn = (e + 1 < end) ? adj[e + 1] : 0;   // prefetch next src id
    float w = dinv[s] * dv;
    u16x4 q = *(const u16x4*)(h + (size_t)s * C + ch0);
    a0 += bf2f(q[0]) * w; a1 += bf2f(q[1]) * w;
    a2 += bf2f(q[2]) * w; a3 += bf2f(q[3]) * w;
    s = sn;
  }
  float va[4] = {a0, a1, a2, a3};
#pragma unroll
  for (int j = 0; j < 4; ++j) {
    int ch = ch0 + j;
    float val = va[j];
    if (BIAS) val += bias[ch];
    if (BNRELU) {
      val = (val - mea[ch]) * rsqrtf(var[ch] + EPSBN) * gam[ch] + bet[ch];
      val = fmaxf(val, 0.f);
    }
    outp[(size_t)v * C + ch] = f2bf(val);
  }
}

// ---------------- launch ----------------
extern "C" void kernel_launch(void* const* d_in, const int* in_sizes, int n_in,
                              void* d_out, int out_size, void* d_ws, size_t ws_size,
                              hipStream_t stream) {
  const float* x   = (const float*)d_in[0];
  const int*   ei  = (const int*)d_in[1];
  const float* W1  = (const float*)d_in[2];
  const float* b1  = (const float*)d_in[3];
  const float* g1  = (const float*)d_in[4];
  const float* be1 = (const float*)d_in[5];
  const float* m1  = (const float*)d_in[6];
  const float* v1  = (const float*)d_in[7];
  const float* W2  = (const float*)d_in[8];
  const float* b2  = (const float*)d_in[9];
  const float* g2  = (const float*)d_in[10];
  const float* be2 = (const float*)d_in[11];
  const float* m2  = (const float*)d_in[12];
  const float* v2  = (const float*)d_in[13];
  const float* W3  = (const float*)d_in[14];
  const float* b3  = (const float*)d_in[15];

  const int IN = 1280, H = 256, OUT = 500, OUTP = 512;
  int E  = in_sizes[1] / 2;
  int nN = in_sizes[0] / IN;
  const int* srcI = ei;
  const int* dstI = ei + E;

  char* p = (char*)d_ws;
  auto carve = [&](size_t bytes) { char* r = p; p += (bytes + 511) & ~(size_t)511; return r; };
  unsigned short* Wt1 = (unsigned short*)carve((size_t)H * IN * 2);
  unsigned short* Wt2 = (unsigned short*)carve((size_t)H * H * 2);
  unsigned short* Wt3 = (unsigned short*)carve((size_t)OUTP * H * 2);
  unsigned* deg  = (unsigned*)carve((size_t)nN * 4);
  float*    dinv = (float*)carve((size_t)nN * 4);
  unsigned* offs = (unsigned*)carve((size_t)(nN + 1) * 4);
  unsigned* cur  = (unsigned*)carve((size_t)nN * 4);
  unsigned* bsum = (unsigned*)carve(256 * 4);
  unsigned* bpre = (unsigned*)carve(256 * 4);
  int*      adj  = (int*)carve((size_t)(E + nN) * 4);
  unsigned short* bufA = (unsigned short*)carve((size_t)nN * H * 2);  // pre-agg h
  unsigned short* bufB = (unsigned short*)carve((size_t)nN * H * 2);  // post-agg act

  int NB = (nN + 255) / 256;
  k_init_deg<<<NB, 256, 0, stream>>>(deg, nN);
  k_count<<<(E + 255) / 256, 256, 0, stream>>>(dstI, deg, E);
  k_dinv<<<NB, 256, 0, stream>>>(deg, dinv, nN);
  k_bsum<<<NB, 256, 0, stream>>>(deg, bsum, nN);
  k_scan_top<<<1, 256, 0, stream>>>(bsum, bpre, NB, offs, nN);
  k_scan_fin<<<NB, 256, 0, stream>>>(deg, bpre, offs, cur, nN);
  k_fill<<<(E + nN + 255) / 256, 256, 0, stream>>>(srcI, dstI, cur, adj, E, nN);
  k_sort<<<NB, 256, 0, stream>>>(offs, adj, nN);

  k_wt<<<(H * IN + 255) / 256, 256, 0, stream>>>(W1, Wt1, IN, H, H);
  k_wt<<<(H * H + 255) / 256, 256, 0, stream>>>(W2, Wt2, H, H, H);
  k_wt<<<(OUTP * H + 255) / 256, 256, 0, stream>>>(W3, Wt3, H, OUT, OUTP);

  int MT = (nN + BM - 1) / BM;          // 391
  int mg = (MT + 7) / 8;                // 49
  int nAgg = (nN + 3) / 4;

  // layer 1:  h1 = x*W1 ; act1 = BNReLU(agg(h1)+b1)
  k_gemm<1, 0><<<mg * 8 * 2, 256, 0, stream>>>(x, Wt1, bufA, nullptr, nN, H, IN, MT, 2);
  k_agg<1, 1><<<nAgg, 256, 0, stream>>>(bufA, adj, offs, dinv, b1, g1, be1, m1, v1, bufB, nN);
  // layer 2:  h2 = act1*W2 ; act2 = BNReLU(agg(h2)+b2)
  k_gemm<0, 0><<<mg * 8 * 2, 256, 0, stream>>>(bufB, Wt2, bufA, nullptr, nN, H, H, MT, 2);
  k_agg<1, 1><<<nAgg, 256, 0, stream>>>(bufA, adj, offs, dinv, b2, g2, be2, m2, v2, bufB, nN);
  // layer 3 (reordered):  out = (agg(act2)) * W3 + b3
  k_agg<0, 0><<<nAgg, 256, 0, stream>>>(bufB, adj, offs, dinv, nullptr, nullptr, nullptr, nullptr, nullptr, bufA, nN);
  k_gemm<0, 1><<<mg * 8 * 4, 256, 0, stream>>>(bufA, Wt3, d_out, b3, nN, OUT, H, MT, 4);
}

// Round 3
// 826.845 us; speedup vs baseline: 1.3223x; 1.2339x over previous
//
#include <hip/hip_runtime.h>
#include <hip/hip_bf16.h>
#include <stdint.h>

typedef __attribute__((ext_vector_type(4))) float f32x4;
typedef __attribute__((ext_vector_type(8))) short s16x8;
typedef __attribute__((ext_vector_type(4))) unsigned short u16x4;

#define EPSBN 1e-5f

__device__ __forceinline__ float bf2f(unsigned short u) {
  union { unsigned int i; float f; } w; w.i = ((unsigned int)u) << 16; return w.f;
}
__device__ __forceinline__ unsigned short f2bf(float f) {
  __hip_bfloat16 h = __float2bfloat16(f);   // RNE
  unsigned short u; __builtin_memcpy(&u, &h, 2); return u;
}
__device__ __forceinline__ void gld_lds16(const unsigned short* g, unsigned short* l) {
  __builtin_amdgcn_global_load_lds(
      (__attribute__((address_space(1))) void*)(g),
      (__attribute__((address_space(3))) void*)(l), 16, 0, 0);
}

// ---------------- graph prep ----------------
__global__ void k_init_deg(unsigned* deg, int n) {
  int i = blockIdx.x * 256 + threadIdx.x;
  if (i < n) deg[i] = 1u;               // self-loop
}
__global__ void k_count(const int* __restrict__ dst, unsigned* __restrict__ deg, int E) {
  int i = blockIdx.x * 256 + threadIdx.x;
  if (i < E) atomicAdd(&deg[dst[i]], 1u);
}
__global__ void k_dinv(const unsigned* __restrict__ deg, float* __restrict__ dinv, int n) {
  int i = blockIdx.x * 256 + threadIdx.x;
  if (i < n) dinv[i] = rsqrtf((float)deg[i]);
}
__global__ void k_bsum(const unsigned* __restrict__ deg, unsigned* __restrict__ bsum, int n) {
  __shared__ unsigned s[256];
  int t = threadIdx.x, i = blockIdx.x * 256 + t;
  s[t] = (i < n) ? deg[i] : 0u;
  __syncthreads();
  for (int st = 128; st > 0; st >>= 1) {
    if (t < st) s[t] += s[t + st];
    __syncthreads();
  }
  if (t == 0) bsum[blockIdx.x] = s[0];
}
__global__ void k_scan_top(const unsigned* __restrict__ bsum, unsigned* __restrict__ bpre,
                           int nb, unsigned* __restrict__ offs, int n) {
  __shared__ unsigned s[256];
  int t = threadIdx.x;
  unsigned v = (t < nb) ? bsum[t] : 0u;
  s[t] = v; __syncthreads();
  for (int d = 1; d < 256; d <<= 1) {
    unsigned a = (t >= d) ? s[t - d] : 0u;
    __syncthreads();
    s[t] += a;
    __syncthreads();
  }
  bpre[t] = s[t] - v;                    // exclusive
  if (t == 255) offs[n] = s[255];        // total = E + n
}
__global__ void k_scan_fin(const unsigned* __restrict__ deg, const unsigned* __restrict__ bpre,
                           unsigned* __restrict__ offs, unsigned* __restrict__ cur, int n) {
  __shared__ unsigned s[256];
  int t = threadIdx.x, i = blockIdx.x * 256 + t;
  unsigned v = (i < n) ? deg[i] : 0u;
  s[t] = v; __syncthreads();
  for (int d = 1; d < 256; d <<= 1) {
    unsigned a = (t >= d) ? s[t - d] : 0u;
    __syncthreads();
    s[t] += a;
    __syncthreads();
  }
  if (i < n) {
    unsigned o = bpre[blockIdx.x] + s[t] - v;
    offs[i] = o; cur[i] = o;
  }
}
__global__ void k_fill(const int* __restrict__ src, const int* __restrict__ dst,
                       unsigned* __restrict__ cur, int* __restrict__ adj, int E, int n) {
  int i = blockIdx.x * 256 + threadIdx.x;
  int s, d;
  if (i < E)          { s = src[i]; d = dst[i]; }
  else if (i < E + n) { s = d = i - E; }        // self-loop
  else return;
  unsigned p = atomicAdd(&cur[d], 1u);
  adj[p] = s;
}
// per-dst insertion sort of adj segments (src-ascending) for L2 sweep locality
#define SORT_CAP 96
__global__ __launch_bounds__(256) void k_sort(const unsigned* __restrict__ offs,
                                              int* __restrict__ adj, int nN) {
  __shared__ int buf[SORT_CAP * 256];    // 96 KB, column-per-thread (stride 256)
  int t = threadIdx.x;
  int v = blockIdx.x * 256 + t;
  if (v >= nN) return;
  unsigned b = offs[v], e = offs[v + 1];
  int len = (int)(e - b);
  if (len > SORT_CAP) return;            // pathological degree: leave unsorted (still correct)
  for (int i = 0; i < len; ++i) buf[i * 256 + t] = adj[b + i];
  for (int i = 1; i < len; ++i) {
    int key = buf[i * 256 + t];
    int j = i - 1;
    while (j >= 0 && buf[j * 256 + t] > key) {
      buf[(j + 1) * 256 + t] = buf[j * 256 + t];
      --j;
    }
    buf[(j + 1) * 256 + t] = key;
  }
  for (int i = 0; i < len; ++i) adj[b + i] = buf[i * 256 + t];
}
// per-edge (src, w=dinv[src]*dinv[dst]) pairs, wave per dst node
__global__ __launch_bounds__(256) void k_edgew(const int* __restrict__ adj,
                                               const unsigned* __restrict__ offs,
                                               const float* __restrict__ dinv,
                                               int2* __restrict__ ew, int nN) {
  int wv = (blockIdx.x * 256 + threadIdx.x) >> 6;
  int lane = threadIdx.x & 63;
  if (wv >= nN) return;
  unsigned beg = offs[wv], end = offs[wv + 1];
  float dv = dinv[wv];
  for (unsigned e = beg + lane; e < end; e += 64) {
    int s = adj[e];
    ew[e] = make_int2(s, __float_as_int(dinv[s] * dv));
  }
}
// W [K][N] fp32 -> Wt [Npad][K] bf16 (rows >= N zero)
__global__ void k_wt(const float* __restrict__ W, unsigned short* __restrict__ Wt,
                     int K, int N, int Npad) {
  int idx = blockIdx.x * 256 + threadIdx.x;
  if (idx >= Npad * K) return;
  int nn = idx / K, k = idx - nn * K;
  float v = (nn < N) ? W[(size_t)k * N + nn] : 0.f;
  Wt[idx] = f2bf(v);
}

// ---------------- GEMM: C[M,N] = A[M,K] * Bt[N,K]^T, bf16 MFMA ----------------
#define BM 128
#define BN 128
#define BK 64

template<int CONVA, int OUTF32>
__global__ __launch_bounds__(256, 2) void k_gemm(
    const void* __restrict__ Aall, const unsigned short* __restrict__ Bt,
    void* __restrict__ Coutv, const float* __restrict__ bias,
    int M, int N, int K, int MT, int NT)
{
  __shared__ __align__(16) unsigned short As[BM * BK];
  __shared__ __align__(16) unsigned short Bs[BN * BK];

  // XCD pairing: all NT col-tiles of an M-tile share d%8 (same XCD, 8 apart)
  int d = blockIdx.x;
  int xc = d & 7, sb = d >> 3;
  int nt = sb % NT, mt = (sb / NT) * 8 + xc;
  if (mt >= MT) return;
  int m0 = mt * BM, n0 = nt * BN;

  int tid = threadIdx.x, lane = tid & 63, wave = tid >> 6;
  int wm = wave >> 1, wn = wave & 1;
  int l15 = lane & 15, l4 = lane >> 4;

  f32x4 acc[4][4];
#pragma unroll
  for (int i = 0; i < 4; ++i)
#pragma unroll
    for (int j = 0; j < 4; ++j) acc[i][j] = 0.f;

  int srow[4], scg[4], sci[4];
#pragma unroll
  for (int i = 0; i < 4; ++i) {
    int ci = (wave + 4 * i) * 64 + lane;
    sci[i] = ci;
    srow[i] = ci >> 3;                         // 8 chunks per 128B row
    scg[i] = (ci & 7) ^ (srow[i] & 7);         // pre-swizzled source chunk
  }
  const float* Af = (const float*)Aall;
  const unsigned short* Au = (const unsigned short*)Aall;

  int nk = K / BK;
  for (int kt = 0; kt < nk; ++kt) {
    __syncthreads();
#pragma unroll
    for (int i = 0; i < 4; ++i) {
      int gr = m0 + srow[i]; gr = gr < M ? gr : M - 1;
      if (CONVA) {
        const float* p = Af + (size_t)gr * K + kt * BK + scg[i] * 8;
        f32x4 f0 = *(const f32x4*)p;
        f32x4 f1 = *(const f32x4*)(p + 4);
        s16x8 pk;
        pk[0] = (short)f2bf(f0[0]); pk[1] = (short)f2bf(f0[1]);
        pk[2] = (short)f2bf(f0[2]); pk[3] = (short)f2bf(f0[3]);
        pk[4] = (short)f2bf(f1[0]); pk[5] = (short)f2bf(f1[1]);
        pk[6] = (short)f2bf(f1[2]); pk[7] = (short)f2bf(f1[3]);
        *(s16x8*)(As + sci[i] * 8) = pk;
      } else {
        gld_lds16(Au + (size_t)gr * K + kt * BK + scg[i] * 8, As + (wave + 4 * i) * 512);
      }
    }
#pragma unroll
    for (int i = 0; i < 4; ++i) {
      int gn = n0 + srow[i];
      gld_lds16(Bt + (size_t)gn * K + kt * BK + scg[i] * 8, Bs + (wave + 4 * i) * 512);
    }
    __syncthreads();

#pragma unroll
    for (int ks = 0; ks < 2; ++ks) {
      s16x8 af[4], bf[4];
#pragma unroll
      for (int f = 0; f < 4; ++f) {
        int r = wm * 64 + f * 16 + l15;
        int ca = (ks * 4 + l4) ^ (r & 7);
        af[f] = *(const s16x8*)(As + r * 64 + ca * 8);
        int nloc = wn * 64 + f * 16 + l15;
        int cb = (ks * 4 + l4) ^ (nloc & 7);
        bf[f] = *(const s16x8*)(Bs + nloc * 64 + cb * 8);
      }
#pragma unroll
      for (int fm = 0; fm < 4; ++fm)
#pragma unroll
        for (int fn = 0; fn < 4; ++fn)
          acc[fm][fn] = __builtin_amdgcn_mfma_f32_16x16x32_bf16(af[fm], bf[fn], acc[fm][fn], 0, 0, 0);
    }
  }

  // epilogue: C/D layout col=lane&15, row=(lane>>4)*4+reg
#pragma unroll
  for (int fm = 0; fm < 4; ++fm) {
#pragma unroll
    for (int fn = 0; fn < 4; ++fn) {
#pragma unroll
      for (int r = 0; r < 4; ++r) {
        int row = m0 + wm * 64 + fm * 16 + l4 * 4 + r;
        int col = n0 + wn * 64 + fn * 16 + l15;
        if (row < M && col < N) {
          if (OUTF32)
            ((float*)Coutv)[(size_t)row * N + col] = acc[fm][fn][r] + bias[col];
          else
            ((unsigned short*)Coutv)[(size_t)row * N + col] = f2bf(acc[fm][fn][r]);
        }
      }
    }
  }
}

// -------- aggregation (C=256), 4-deep pipelined row gathers --------
__device__ __forceinline__ void accum4(float& a0, float& a1, float& a2, float& a3,
                                       u16x4 q, float w) {
  a0 += bf2f(q[0]) * w; a1 += bf2f(q[1]) * w;
  a2 += bf2f(q[2]) * w; a3 += bf2f(q[3]) * w;
}

template<int BNRELU, int BIAS>
__global__ __launch_bounds__(256) void k_agg(
    const unsigned short* __restrict__ h, const int2* __restrict__ ew,
    const unsigned* __restrict__ offs, const float* __restrict__ bias,
    const float* __restrict__ gam, const float* __restrict__ bet,
    const float* __restrict__ mea, const float* __restrict__ var,
    unsigned short* __restrict__ outp, int nN)
{
  const int C = 256;
  int wave = threadIdx.x >> 6, lane = threadIdx.x & 63;
  int v = blockIdx.x * 4 + wave;
  if (v >= nN) return;
  unsigned beg = offs[v], end = offs[v + 1];
  int len = (int)(end - beg);
  int ch0 = lane * 4;
  const unsigned short* hb = h + ch0;
  float a0 = 0, a1 = 0, a2 = 0, a3 = 0;

  for (int base = 0; base < len; base += 64) {
    int m = min(64, len - base);
    int2 myp = make_int2(0, 0);               // pads: src 0, weight 0
    if (lane < m) myp = ew[beg + base + lane];
    int ng = (m + 3) >> 2;

    int sA0 = __shfl(myp.x, 0), sA1 = __shfl(myp.x, 1);
    int sA2 = __shfl(myp.x, 2), sA3 = __shfl(myp.x, 3);
    float wA0 = __int_as_float(__shfl(myp.y, 0));
    float wA1 = __int_as_float(__shfl(myp.y, 1));
    float wA2 = __int_as_float(__shfl(myp.y, 2));
    float wA3 = __int_as_float(__shfl(myp.y, 3));
    u16x4 qA0 = *(const u16x4*)(hb + (size_t)sA0 * C);
    u16x4 qA1 = *(const u16x4*)(hb + (size_t)sA1 * C);
    u16x4 qA2 = *(const u16x4*)(hb + (size_t)sA2 * C);
    u16x4 qA3 = *(const u16x4*)(hb + (size_t)sA3 * C);

    for (int g = 1; g < ng; ++g) {
      int b = g << 2;
      int sB0 = __shfl(myp.x, b + 0), sB1 = __shfl(myp.x, b + 1);
      int sB2 = __shfl(myp.x, b + 2), sB3 = __shfl(myp.x, b + 3);
      float wB0 = __int_as_float(__shfl(myp.y, b + 0));
      float wB1 = __int_as_float(__shfl(myp.y, b + 1));
      float wB2 = __int_as_float(__shfl(myp.y, b + 2));
      float wB3 = __int_as_float(__shfl(myp.y, b + 3));
      u16x4 qB0 = *(const u16x4*)(hb + (size_t)sB0 * C);
      u16x4 qB1 = *(const u16x4*)(hb + (size_t)sB1 * C);
      u16x4 qB2 = *(const u16x4*)(hb + (size_t)sB2 * C);
      u16x4 qB3 = *(const u16x4*)(hb + (size_t)sB3 * C);
      accum4(a0, a1, a2, a3, qA0, wA0);
      accum4(a0, a1, a2, a3, qA1, wA1);
      accum4(a0, a1, a2, a3, qA2, wA2);
      accum4(a0, a1, a2, a3, qA3, wA3);
      qA0 = qB0; wA0 = wB0; qA1 = qB1; wA1 = wB1;
      qA2 = qB2; wA2 = wB2; qA3 = qB3; wA3 = wB3;
    }
    accum4(a0, a1, a2, a3, qA0, wA0);
    accum4(a0, a1, a2, a3, qA1, wA1);
    accum4(a0, a1, a2, a3, qA2, wA2);
    accum4(a0, a1, a2, a3, qA3, wA3);
  }

  float va[4] = {a0, a1, a2, a3};
#pragma unroll
  for (int j = 0; j < 4; ++j) {
    int ch = ch0 + j;
    float val = va[j];
    if (BIAS) val += bias[ch];
    if (BNRELU) {
      val = (val - mea[ch]) * rsqrtf(var[ch] + EPSBN) * gam[ch] + bet[ch];
      val = fmaxf(val, 0.f);
    }
    outp[(size_t)v * C + ch] = f2bf(val);
  }
}

// ---------------- launch ----------------
extern "C" void kernel_launch(void* const* d_in, const int* in_sizes, int n_in,
                              void* d_out, int out_size, void* d_ws, size_t ws_size,
                              hipStream_t stream) {
  const float* x   = (const float*)d_in[0];
  const int*   ei  = (const int*)d_in[1];
  const float* W1  = (const float*)d_in[2];
  const float* b1  = (const float*)d_in[3];
  const float* g1  = (const float*)d_in[4];
  const float* be1 = (const float*)d_in[5];
  const float* m1  = (const float*)d_in[6];
  const float* v1  = (const float*)d_in[7];
  const float* W2  = (const float*)d_in[8];
  const float* b2  = (const float*)d_in[9];
  const float* g2  = (const float*)d_in[10];
  const float* be2 = (const float*)d_in[11];
  const float* m2  = (const float*)d_in[12];
  const float* v2  = (const float*)d_in[13];
  const float* W3  = (const float*)d_in[14];
  const float* b3  = (const float*)d_in[15];

  const int IN = 1280, H = 256, OUT = 500, OUTP = 512;
  int E  = in_sizes[1] / 2;
  int nN = in_sizes[0] / IN;
  const int* srcI = ei;
  const int* dstI = ei + E;

  char* p = (char*)d_ws;
  auto carve = [&](size_t bytes) { char* r = p; p += (bytes + 511) & ~(size_t)511; return r; };
  unsigned short* Wt1 = (unsigned short*)carve((size_t)H * IN * 2);
  unsigned short* Wt2 = (unsigned short*)carve((size_t)H * H * 2);
  unsigned short* Wt3 = (unsigned short*)carve((size_t)OUTP * H * 2);
  unsigned* deg  = (unsigned*)carve((size_t)nN * 4);
  float*    dinv = (float*)carve((size_t)nN * 4);
  unsigned* offs = (unsigned*)carve((size_t)(nN + 1) * 4);
  unsigned* cur  = (unsigned*)carve((size_t)nN * 4);
  unsigned* bsum = (unsigned*)carve(256 * 4);
  unsigned* bpre = (unsigned*)carve(256 * 4);
  int*      adj  = (int*)carve((size_t)(E + nN) * 4);
  int2*     ew   = (int2*)carve((size_t)(E + nN) * 8);
  unsigned short* bufA = (unsigned short*)carve((size_t)nN * H * 2);  // pre-agg h
  unsigned short* bufB = (unsigned short*)carve((size_t)nN * H * 2);  // post-agg act

  int NB = (nN + 255) / 256;
  k_init_deg<<<NB, 256, 0, stream>>>(deg, nN);
  k_count<<<(E + 255) / 256, 256, 0, stream>>>(dstI, deg, E);
  k_dinv<<<NB, 256, 0, stream>>>(deg, dinv, nN);
  k_bsum<<<NB, 256, 0, stream>>>(deg, bsum, nN);
  k_scan_top<<<1, 256, 0, stream>>>(bsum, bpre, NB, offs, nN);
  k_scan_fin<<<NB, 256, 0, stream>>>(deg, bpre, offs, cur, nN);
  k_fill<<<(E + nN + 255) / 256, 256, 0, stream>>>(srcI, dstI, cur, adj, E, nN);
  k_sort<<<NB, 256, 0, stream>>>(offs, adj, nN);
  k_edgew<<<(nN + 3) / 4, 256, 0, stream>>>(adj, offs, dinv, ew, nN);

  k_wt<<<(H * IN + 255) / 256, 256, 0, stream>>>(W1, Wt1, IN, H, H);
  k_wt<<<(H * H + 255) / 256, 256, 0, stream>>>(W2, Wt2, H, H, H);
  k_wt<<<(OUTP * H + 255) / 256, 256, 0, stream>>>(W3, Wt3, H, OUT, OUTP);

  int MT = (nN + BM - 1) / BM;          // 391
  int mg = (MT + 7) / 8;                // 49
  int nAgg = (nN + 3) / 4;

  // layer 1:  h1 = x*W1 ; act1 = BNReLU(agg(h1)+b1)
  k_gemm<1, 0><<<mg * 8 * 2, 256, 0, stream>>>(x, Wt1, bufA, nullptr, nN, H, IN, MT, 2);
  k_agg<1, 1><<<nAgg, 256, 0, stream>>>(bufA, ew, offs, b1, g1, be1, m1, v1, bufB, nN);
  // layer 2:  h2 = act1*W2 ; act2 = BNReLU(agg(h2)+b2)
  k_gemm<0, 0><<<mg * 8 * 2, 256, 0, stream>>>(bufB, Wt2, bufA, nullptr, nN, H, H, MT, 2);
  k_agg<1, 1><<<nAgg, 256, 0, stream>>>(bufA, ew, offs, b2, g2, be2, m2, v2, bufB, nN);
  // layer 3 (reordered):  out = (agg(act2)) * W3 + b3
  k_agg<0, 0><<<nAgg, 256, 0, stream>>>(bufB, ew, offs, nullptr, nullptr, nullptr, nullptr, nullptr, bufA, nN);
  k_gemm<0, 1><<<mg * 8 * 4, 256, 0, stream>>>(bufA, Wt3, d_out, b3, nN, OUT, H, MT, 4);
}

// Round 4
// 701.887 us; speedup vs baseline: 1.5577x; 1.1780x over previous
//
#include <hip/hip_runtime.h>
#include <hip/hip_bf16.h>
#include <stdint.h>

typedef __attribute__((ext_vector_type(4))) float f32x4;
typedef __attribute__((ext_vector_type(8))) short s16x8;
typedef __attribute__((ext_vector_type(4))) unsigned short u16x4;

#define EPSBN 1e-5f

__device__ __forceinline__ float bf2f(unsigned short u) {
  union { unsigned int i; float f; } w; w.i = ((unsigned int)u) << 16; return w.f;
}
__device__ __forceinline__ unsigned short f2bf(float f) {
  __hip_bfloat16 h = __float2bfloat16(f);   // RNE
  unsigned short u; __builtin_memcpy(&u, &h, 2); return u;
}
__device__ __forceinline__ void gld_lds16(const void* g, void* l) {
  __builtin_amdgcn_global_load_lds(
      (const __attribute__((address_space(1))) void*)(g),
      (__attribute__((address_space(3))) void*)(l), 16, 0, 0);
}

// ---------------- graph prep ----------------
__global__ void k_init_deg(unsigned* deg, int n) {
  int i = blockIdx.x * 256 + threadIdx.x;
  if (i < n) deg[i] = 1u;               // self-loop
}
__global__ void k_count(const int* __restrict__ dst, unsigned* __restrict__ deg, int E) {
  int i = blockIdx.x * 256 + threadIdx.x;
  if (i < E) atomicAdd(&deg[dst[i]], 1u);
}
__global__ void k_dinv(const unsigned* __restrict__ deg, float* __restrict__ dinv, int n) {
  int i = blockIdx.x * 256 + threadIdx.x;
  if (i < n) dinv[i] = rsqrtf((float)deg[i]);
}
__global__ void k_bsum(const unsigned* __restrict__ deg, unsigned* __restrict__ bsum, int n) {
  __shared__ unsigned s[256];
  int t = threadIdx.x, i = blockIdx.x * 256 + t;
  s[t] = (i < n) ? deg[i] : 0u;
  __syncthreads();
  for (int st = 128; st > 0; st >>= 1) {
    if (t < st) s[t] += s[t + st];
    __syncthreads();
  }
  if (t == 0) bsum[blockIdx.x] = s[0];
}
__global__ void k_scan_top(const unsigned* __restrict__ bsum, unsigned* __restrict__ bpre,
                           int nb, unsigned* __restrict__ offs, int n) {
  __shared__ unsigned s[256];
  int t = threadIdx.x;
  unsigned v = (t < nb) ? bsum[t] : 0u;
  s[t] = v; __syncthreads();
  for (int d = 1; d < 256; d <<= 1) {
    unsigned a = (t >= d) ? s[t - d] : 0u;
    __syncthreads();
    s[t] += a;
    __syncthreads();
  }
  bpre[t] = s[t] - v;                    // exclusive
  if (t == 255) offs[n] = s[255];        // total = E + n
}
__global__ void k_scan_fin(const unsigned* __restrict__ deg, const unsigned* __restrict__ bpre,
                           unsigned* __restrict__ offs, unsigned* __restrict__ cur, int n) {
  __shared__ unsigned s[256];
  int t = threadIdx.x, i = blockIdx.x * 256 + t;
  unsigned v = (i < n) ? deg[i] : 0u;
  s[t] = v; __syncthreads();
  for (int d = 1; d < 256; d <<= 1) {
    unsigned a = (t >= d) ? s[t - d] : 0u;
    __syncthreads();
    s[t] += a;
    __syncthreads();
  }
  if (i < n) {
    unsigned o = bpre[blockIdx.x] + s[t] - v;
    offs[i] = o; cur[i] = o;
  }
}
__global__ void k_fill(const int* __restrict__ src, const int* __restrict__ dst,
                       unsigned* __restrict__ cur, int* __restrict__ adj, int E, int n) {
  int i = blockIdx.x * 256 + threadIdx.x;
  int s, d;
  if (i < E)          { s = src[i]; d = dst[i]; }
  else if (i < E + n) { s = d = i - E; }        // self-loop
  else return;
  unsigned p = atomicAdd(&cur[d], 1u);
  adj[p] = s;
}
// wave-per-node: bitonic sort (src ascending, 64-lane shfl network) + ew = (src, w)
__global__ __launch_bounds__(256) void k_sortw(const unsigned* __restrict__ offs,
                                               const int* __restrict__ adj,
                                               const float* __restrict__ dinv,
                                               int2* __restrict__ ew, int nN) {
  int wv = (blockIdx.x * 256 + threadIdx.x) >> 6;
  int lane = threadIdx.x & 63;
  if (wv >= nN) return;
  unsigned beg = offs[wv], end = offs[wv + 1];
  int len = (int)(end - beg);
  float dv = dinv[wv];
  if (len <= 64) {
    int k = (lane < len) ? adj[beg + lane] : 0x7FFFFFFF;
#pragma unroll
    for (int size = 2; size <= 64; size <<= 1) {
#pragma unroll
      for (int stride = size >> 1; stride > 0; stride >>= 1) {
        int other = __shfl_xor(k, stride);
        bool up = (lane & size) == 0;
        bool lower = (lane & stride) == 0;
        k = (lower == up) ? min(k, other) : max(k, other);
      }
    }
    if (lane < len) ew[beg + lane] = make_int2(k, __float_as_int(dinv[k] * dv));
  } else {
    for (unsigned e = beg + lane; e < end; e += 64) {
      int s = adj[e];
      ew[e] = make_int2(s, __float_as_int(dinv[s] * dv));
    }
  }
}
// W [K][N] fp32 -> Wt [Npad][K] bf16 (rows >= N zero)
__global__ void k_wt(const float* __restrict__ W, unsigned short* __restrict__ Wt,
                     int K, int N, int Npad) {
  int idx = blockIdx.x * 256 + threadIdx.x;
  if (idx >= Npad * K) return;
  int nn = idx / K, k = idx - nn * K;
  float v = (nn < N) ? W[(size_t)k * N + nn] : 0.f;
  Wt[idx] = f2bf(v);
}

// ---------------- GEMM (bf16 A): C[M,N] = A[M,K] * Bt[N,K]^T ----------------
#define BM 128
#define BN 128
#define BK 64

template<int OUTF32>
__global__ __launch_bounds__(256, 4) void k_gemm(
    const unsigned short* __restrict__ Au, const unsigned short* __restrict__ Bt,
    void* __restrict__ Coutv, const float* __restrict__ bias,
    int M, int N, int K, int MT, int NT)
{
  __shared__ __align__(16) unsigned short As[BM * BK];
  __shared__ __align__(16) unsigned short Bs[BN * BK];

  int d = blockIdx.x;
  int xc = d & 7, sb = d >> 3;
  int nt = sb % NT, mt = (sb / NT) * 8 + xc;
  if (mt >= MT) return;
  int m0 = mt * BM, n0 = nt * BN;

  int tid = threadIdx.x, lane = tid & 63, wave = tid >> 6;
  int wm = wave >> 1, wn = wave & 1;
  int l15 = lane & 15, l4 = lane >> 4;

  f32x4 acc[4][4];
#pragma unroll
  for (int i = 0; i < 4; ++i)
#pragma unroll
    for (int j = 0; j < 4; ++j) acc[i][j] = 0.f;

  int srow[4], scg[4];
#pragma unroll
  for (int i = 0; i < 4; ++i) {
    int ci = (wave + 4 * i) * 64 + lane;
    srow[i] = ci >> 3;                         // 8 chunks per 128B row
    scg[i] = (ci & 7) ^ (srow[i] & 7);         // pre-swizzled source chunk
  }

  int nk = K / BK;
  for (int kt = 0; kt < nk; ++kt) {
    __syncthreads();
#pragma unroll
    for (int i = 0; i < 4; ++i) {
      int gr = m0 + srow[i]; gr = gr < M ? gr : M - 1;
      gld_lds16(Au + (size_t)gr * K + kt * BK + scg[i] * 8, As + (wave + 4 * i) * 512);
    }
#pragma unroll
    for (int i = 0; i < 4; ++i) {
      int gn = n0 + srow[i];
      gld_lds16(Bt + (size_t)gn * K + kt * BK + scg[i] * 8, Bs + (wave + 4 * i) * 512);
    }
    __syncthreads();

#pragma unroll
    for (int ks = 0; ks < 2; ++ks) {
      s16x8 af[4], bf[4];
#pragma unroll
      for (int f = 0; f < 4; ++f) {
        int r = wm * 64 + f * 16 + l15;
        int ca = (ks * 4 + l4) ^ (r & 7);
        af[f] = *(const s16x8*)(As + r * 64 + ca * 8);
        int nloc = wn * 64 + f * 16 + l15;
        int cb = (ks * 4 + l4) ^ (nloc & 7);
        bf[f] = *(const s16x8*)(Bs + nloc * 64 + cb * 8);
      }
#pragma unroll
      for (int fm = 0; fm < 4; ++fm)
#pragma unroll
        for (int fn = 0; fn < 4; ++fn)
          acc[fm][fn] = __builtin_amdgcn_mfma_f32_16x16x32_bf16(af[fm], bf[fn], acc[fm][fn], 0, 0, 0);
    }
  }

#pragma unroll
  for (int fm = 0; fm < 4; ++fm) {
#pragma unroll
    for (int fn = 0; fn < 4; ++fn) {
#pragma unroll
      for (int r = 0; r < 4; ++r) {
        int row = m0 + wm * 64 + fm * 16 + l4 * 4 + r;
        int col = n0 + wn * 64 + fn * 16 + l15;
        if (row < M && col < N) {
          if (OUTF32)
            ((float*)Coutv)[(size_t)row * N + col] = acc[fm][fn][r] + bias[col];
          else
            ((unsigned short*)Coutv)[(size_t)row * N + col] = f2bf(acc[fm][fn][r]);
        }
      }
    }
  }
}

// ------- GEMM variant: A is fp32 in global, staged fp32 via global_load_lds, cvt at frag read -------
__global__ __launch_bounds__(256, 3) void k_gemmF(
    const float* __restrict__ Af, const unsigned short* __restrict__ Bt,
    unsigned short* __restrict__ Cout, int M, int N, int K, int MT, int NT)
{
  __shared__ __align__(16) float As[BM * BK];           // 32 KB fp32
  __shared__ __align__(16) unsigned short Bs[BN * BK];  // 16 KB

  int d = blockIdx.x;
  int xc = d & 7, sb = d >> 3;
  int nt = sb % NT, mt = (sb / NT) * 8 + xc;
  if (mt >= MT) return;
  int m0 = mt * BM, n0 = nt * BN;

  int tid = threadIdx.x, lane = tid & 63, wave = tid >> 6;
  int wm = wave >> 1, wn = wave & 1;
  int l15 = lane & 15, l4 = lane >> 4;

  f32x4 acc[4][4];
#pragma unroll
  for (int i = 0; i < 4; ++i)
#pragma unroll
    for (int j = 0; j < 4; ++j) acc[i][j] = 0.f;

  // A: 2048 16B-chunks (16 chunks per 256B row), 8 per thread
  int arow[8], acs[8];
#pragma unroll
  for (int i = 0; i < 8; ++i) {
    int ci = (i * 4 + wave) * 64 + lane;
    arow[i] = ci >> 4;
    acs[i] = (ci & 15) ^ ((arow[i] & 7) << 1);  // pre-swizzled source chunk (pair-preserving)
  }
  // B: 1024 chunks (8 per 128B row), 4 per thread
  int brow[4], bcg[4];
#pragma unroll
  for (int i = 0; i < 4; ++i) {
    int ci = (i * 4 + wave) * 64 + lane;
    brow[i] = ci >> 3;
    bcg[i] = (ci & 7) ^ (brow[i] & 7);
  }

  int nk = K / BK;
  for (int kt = 0; kt < nk; ++kt) {
    __syncthreads();
#pragma unroll
    for (int i = 0; i < 8; ++i) {
      int gr = m0 + arow[i]; gr = gr < M ? gr : M - 1;
      gld_lds16(Af + (size_t)gr * K + kt * BK + acs[i] * 4, As + (i * 4 + wave) * 256);
    }
#pragma unroll
    for (int i = 0; i < 4; ++i) {
      int gn = n0 + brow[i];
      gld_lds16(Bt + (size_t)gn * K + kt * BK + bcg[i] * 8, Bs + (i * 4 + wave) * 512);
    }
    __syncthreads();

#pragma unroll
    for (int ks = 0; ks < 2; ++ks) {
      s16x8 af[4], bf[4];
#pragma unroll
      for (int f = 0; f < 4; ++f) {
        int r = wm * 64 + f * 16 + l15;
        int c0 = (2 * (ks * 4 + l4)) ^ ((r & 7) << 1);
        f32x4 a0 = *(const f32x4*)(As + r * 64 + c0 * 4);
        f32x4 a1 = *(const f32x4*)(As + r * 64 + c0 * 4 + 4);
        s16x8 pk;
        pk[0] = (short)f2bf(a0[0]); pk[1] = (short)f2bf(a0[1]);
        pk[2] = (short)f2bf(a0[2]); pk[3] = (short)f2bf(a0[3]);
        pk[4] = (short)f2bf(a1[0]); pk[5] = (short)f2bf(a1[1]);
        pk[6] = (short)f2bf(a1[2]); pk[7] = (short)f2bf(a1[3]);
        af[f] = pk;
        int nloc = wn * 64 + f * 16 + l15;
        int cb = (ks * 4 + l4) ^ (nloc & 7);
        bf[f] = *(const s16x8*)(Bs + nloc * 64 + cb * 8);
      }
#pragma unroll
      for (int fm = 0; fm < 4; ++fm)
#pragma unroll
        for (int fn = 0; fn < 4; ++fn)
          acc[fm][fn] = __builtin_amdgcn_mfma_f32_16x16x32_bf16(af[fm], bf[fn], acc[fm][fn], 0, 0, 0);
    }
  }

#pragma unroll
  for (int fm = 0; fm < 4; ++fm) {
#pragma unroll
    for (int fn = 0; fn < 4; ++fn) {
#pragma unroll
      for (int r = 0; r < 4; ++r) {
        int row = m0 + wm * 64 + fm * 16 + l4 * 4 + r;
        int col = n0 + wn * 64 + fn * 16 + l15;
        if (row < M && col < N)
          Cout[(size_t)row * N + col] = f2bf(acc[fm][fn][r]);
      }
    }
  }
}

// -------- aggregation (C=256), 8-deep pipelined row gathers --------
__device__ __forceinline__ void accum4(float& a0, float& a1, float& a2, float& a3,
                                       u16x4 q, float w) {
  a0 += bf2f(q[0]) * w; a1 += bf2f(q[1]) * w;
  a2 += bf2f(q[2]) * w; a3 += bf2f(q[3]) * w;
}

template<int BNRELU, int BIAS>
__global__ __launch_bounds__(256) void k_agg(
    const unsigned short* __restrict__ h, const int2* __restrict__ ew,
    const unsigned* __restrict__ offs, const float* __restrict__ bias,
    const float* __restrict__ gam, const float* __restrict__ bet,
    const float* __restrict__ mea, const float* __restrict__ var,
    unsigned short* __restrict__ outp, int nN)
{
  const int C = 256;
  int wave = threadIdx.x >> 6, lane = threadIdx.x & 63;
  int v = blockIdx.x * 4 + wave;
  if (v >= nN) return;
  unsigned beg = offs[v], end = offs[v + 1];
  int len = (int)(end - beg);
  int ch0 = lane * 4;
  const unsigned short* hb = h + ch0;
  float a0 = 0, a1 = 0, a2 = 0, a3 = 0;

  for (int base = 0; base < len; base += 64) {
    int m = min(64, len - base);
    int2 myp = make_int2(0, 0);               // pads: src 0, weight 0
    if (lane < m) myp = ew[beg + base + lane];
    int ng = (m + 7) >> 3;

    u16x4 q[8]; float w[8];
#pragma unroll
    for (int r = 0; r < 8; ++r) {
      int s = __shfl(myp.x, r);
      w[r] = __int_as_float(__shfl(myp.y, r));
      q[r] = *(const u16x4*)(hb + (size_t)s * C);
    }
    for (int g = 1; g < ng; ++g) {
      u16x4 q2[8]; float w2[8];
#pragma unroll
      for (int r = 0; r < 8; ++r) {
        int b = g * 8 + r;
        int s = __shfl(myp.x, b);
        w2[r] = __int_as_float(__shfl(myp.y, b));
        q2[r] = *(const u16x4*)(hb + (size_t)s * C);
      }
#pragma unroll
      for (int r = 0; r < 8; ++r) accum4(a0, a1, a2, a3, q[r], w[r]);
#pragma unroll
      for (int r = 0; r < 8; ++r) { q[r] = q2[r]; w[r] = w2[r]; }
    }
#pragma unroll
    for (int r = 0; r < 8; ++r) accum4(a0, a1, a2, a3, q[r], w[r]);
  }

  float va[4] = {a0, a1, a2, a3};
#pragma unroll
  for (int j = 0; j < 4; ++j) {
    int ch = ch0 + j;
    float val = va[j];
    if (BIAS) val += bias[ch];
    if (BNRELU) {
      val = (val - mea[ch]) * rsqrtf(var[ch] + EPSBN) * gam[ch] + bet[ch];
      val = fmaxf(val, 0.f);
    }
    outp[(size_t)v * C + ch] = f2bf(val);
  }
}

// ---------------- launch ----------------
extern "C" void kernel_launch(void* const* d_in, const int* in_sizes, int n_in,
                              void* d_out, int out_size, void* d_ws, size_t ws_size,
                              hipStream_t stream) {
  const float* x   = (const float*)d_in[0];
  const int*   ei  = (const int*)d_in[1];
  const float* W1  = (const float*)d_in[2];
  const float* b1  = (const float*)d_in[3];
  const float* g1  = (const float*)d_in[4];
  const float* be1 = (const float*)d_in[5];
  const float* m1  = (const float*)d_in[6];
  const float* v1  = (const float*)d_in[7];
  const float* W2  = (const float*)d_in[8];
  const float* b2  = (const float*)d_in[9];
  const float* g2  = (const float*)d_in[10];
  const float* be2 = (const float*)d_in[11];
  const float* m2  = (const float*)d_in[12];
  const float* v2  = (const float*)d_in[13];
  const float* W3  = (const float*)d_in[14];
  const float* b3  = (const float*)d_in[15];

  const int IN = 1280, H = 256, OUT = 500, OUTP = 512;
  int E  = in_sizes[1] / 2;
  int nN = in_sizes[0] / IN;
  const int* srcI = ei;
  const int* dstI = ei + E;

  char* p = (char*)d_ws;
  auto carve = [&](size_t bytes) { char* r = p; p += (bytes + 511) & ~(size_t)511; return r; };
  unsigned short* Wt1 = (unsigned short*)carve((size_t)H * IN * 2);
  unsigned short* Wt2 = (unsigned short*)carve((size_t)H * H * 2);
  unsigned short* Wt3 = (unsigned short*)carve((size_t)OUTP * H * 2);
  unsigned* deg  = (unsigned*)carve((size_t)nN * 4);
  float*    dinv = (float*)carve((size_t)nN * 4);
  unsigned* offs = (unsigned*)carve((size_t)(nN + 1) * 4);
  unsigned* cur  = (unsigned*)carve((size_t)nN * 4);
  unsigned* bsum = (unsigned*)carve(256 * 4);
  unsigned* bpre = (unsigned*)carve(256 * 4);
  int*      adj  = (int*)carve((size_t)(E + nN) * 4);
  int2*     ew   = (int2*)carve((size_t)(E + nN) * 8);
  unsigned short* bufA = (unsigned short*)carve((size_t)nN * H * 2);  // pre-agg h
  unsigned short* bufB = (unsigned short*)carve((size_t)nN * H * 2);  // post-agg act

  int NB = (nN + 255) / 256;
  k_init_deg<<<NB, 256, 0, stream>>>(deg, nN);
  k_count<<<(E + 255) / 256, 256, 0, stream>>>(dstI, deg, E);
  k_dinv<<<NB, 256, 0, stream>>>(deg, dinv, nN);
  k_bsum<<<NB, 256, 0, stream>>>(deg, bsum, nN);
  k_scan_top<<<1, 256, 0, stream>>>(bsum, bpre, NB, offs, nN);
  k_scan_fin<<<NB, 256, 0, stream>>>(deg, bpre, offs, cur, nN);
  k_fill<<<(E + nN + 255) / 256, 256, 0, stream>>>(srcI, dstI, cur, adj, E, nN);
  k_sortw<<<(nN + 3) / 4, 256, 0, stream>>>(offs, adj, dinv, ew, nN);

  k_wt<<<(H * IN + 255) / 256, 256, 0, stream>>>(W1, Wt1, IN, H, H);
  k_wt<<<(H * H + 255) / 256, 256, 0, stream>>>(W2, Wt2, H, H, H);
  k_wt<<<(OUTP * H + 255) / 256, 256, 0, stream>>>(W3, Wt3, H, OUT, OUTP);

  int MT = (nN + BM - 1) / BM;          // 391
  int mg = (MT + 7) / 8;                // 49
  int nAgg = (nN + 3) / 4;

  // layer 1:  h1 = x*W1 ; act1 = BNReLU(agg(h1)+b1)
  k_gemmF<<<mg * 8 * 2, 256, 0, stream>>>(x, Wt1, bufA, nN, H, IN, MT, 2);
  k_agg<1, 1><<<nAgg, 256, 0, stream>>>(bufA, ew, offs, b1, g1, be1, m1, v1, bufB, nN);
  // layer 2:  h2 = act1*W2 ; act2 = BNReLU(agg(h2)+b2)
  k_gemm<0><<<mg * 8 * 2, 256, 0, stream>>>(bufB, Wt2, bufA, nullptr, nN, H, H, MT, 2);
  k_agg<1, 1><<<nAgg, 256, 0, stream>>>(bufA, ew, offs, b2, g2, be2, m2, v2, bufB, nN);
  // layer 3 (reordered):  out = (agg(act2)) * W3 + b3
  k_agg<0, 0><<<nAgg, 256, 0, stream>>>(bufB, ew, offs, nullptr, nullptr, nullptr, nullptr, nullptr, bufA, nN);
  k_gemm<1><<<mg * 8 * 4, 256, 0, stream>>>(bufA, Wt3, d_out, b3, nN, OUT, H, MT, 4);
}

// Round 5
// 697.537 us; speedup vs baseline: 1.5675x; 1.0062x over previous
//
#include <hip/hip_runtime.h>
#include <hip/hip_bf16.h>
#include <stdint.h>

typedef __attribute__((ext_vector_type(4))) float f32x4;
typedef __attribute__((ext_vector_type(8))) short s16x8;
typedef __attribute__((ext_vector_type(4))) unsigned short u16x4;

#define EPSBN 1e-5f

__device__ __forceinline__ float bf2f(unsigned short u) {
  union { unsigned int i; float f; } w; w.i = ((unsigned int)u) << 16; return w.f;
}
__device__ __forceinline__ unsigned short f2bf(float f) {
  __hip_bfloat16 h = __float2bfloat16(f);   // RNE
  unsigned short u; __builtin_memcpy(&u, &h, 2); return u;
}
__device__ __forceinline__ void gld_lds16(const void* g, void* l) {
  __builtin_amdgcn_global_load_lds(
      (const __attribute__((address_space(1))) void*)(g),
      (__attribute__((address_space(3))) void*)(l), 16, 0, 0);
}

// ---------------- graph prep ----------------
__global__ void k_init_deg(unsigned* deg, int n) {
  int i = blockIdx.x * 256 + threadIdx.x;
  if (i < n) deg[i] = 1u;               // self-loop
}
__global__ void k_count(const int* __restrict__ dst, unsigned* __restrict__ deg, int E) {
  int i = blockIdx.x * 256 + threadIdx.x;
  if (i < E) atomicAdd(&deg[dst[i]], 1u);
}
// fused: dinv + per-block degree sums
__global__ void k_prep2(const unsigned* __restrict__ deg, float* __restrict__ dinv,
                        unsigned* __restrict__ bsum, int n) {
  __shared__ unsigned s[256];
  int t = threadIdx.x, i = blockIdx.x * 256 + t;
  unsigned d = (i < n) ? deg[i] : 0u;
  if (i < n) dinv[i] = rsqrtf((float)d);
  s[t] = d;
  __syncthreads();
  for (int st = 128; st > 0; st >>= 1) {
    if (t < st) s[t] += s[t + st];
    __syncthreads();
  }
  if (t == 0) bsum[blockIdx.x] = s[0];
}
__global__ void k_scan_top(const unsigned* __restrict__ bsum, unsigned* __restrict__ bpre,
                           int nb, unsigned* __restrict__ offs, int n) {
  __shared__ unsigned s[256];
  int t = threadIdx.x;
  unsigned v = (t < nb) ? bsum[t] : 0u;
  s[t] = v; __syncthreads();
  for (int d = 1; d < 256; d <<= 1) {
    unsigned a = (t >= d) ? s[t - d] : 0u;
    __syncthreads();
    s[t] += a;
    __syncthreads();
  }
  bpre[t] = s[t] - v;                    // exclusive
  if (t == 255) offs[n] = s[255];        // total = E + n
}
__global__ void k_scan_fin(const unsigned* __restrict__ deg, const unsigned* __restrict__ bpre,
                           unsigned* __restrict__ offs, unsigned* __restrict__ cur, int n) {
  __shared__ unsigned s[256];
  int t = threadIdx.x, i = blockIdx.x * 256 + t;
  unsigned v = (i < n) ? deg[i] : 0u;
  s[t] = v; __syncthreads();
  for (int d = 1; d < 256; d <<= 1) {
    unsigned a = (t >= d) ? s[t - d] : 0u;
    __syncthreads();
    s[t] += a;
    __syncthreads();
  }
  if (i < n) {
    unsigned o = bpre[blockIdx.x] + s[t] - v;
    offs[i] = o; cur[i] = o;
  }
}
__global__ void k_fill(const int* __restrict__ src, const int* __restrict__ dst,
                       unsigned* __restrict__ cur, int* __restrict__ adj, int E, int n) {
  int i = blockIdx.x * 256 + threadIdx.x;
  int s, d;
  if (i < E)          { s = src[i]; d = dst[i]; }
  else if (i < E + n) { s = d = i - E; }        // self-loop
  else return;
  unsigned p = atomicAdd(&cur[d], 1u);
  adj[p] = s;
}
// wave-per-node: bitonic sort (src ascending, 64-lane shfl network) + ew = (src, w)
__global__ __launch_bounds__(256) void k_sortw(const unsigned* __restrict__ offs,
                                               const int* __restrict__ adj,
                                               const float* __restrict__ dinv,
                                               int2* __restrict__ ew, int nN) {
  int wv = (blockIdx.x * 256 + threadIdx.x) >> 6;
  int lane = threadIdx.x & 63;
  if (wv >= nN) return;
  unsigned beg = offs[wv], end = offs[wv + 1];
  int len = (int)(end - beg);
  float dv = dinv[wv];
  if (len <= 64) {
    int k = (lane < len) ? adj[beg + lane] : 0x7FFFFFFF;
#pragma unroll
    for (int size = 2; size <= 64; size <<= 1) {
#pragma unroll
      for (int stride = size >> 1; stride > 0; stride >>= 1) {
        int other = __shfl_xor(k, stride);
        bool up = (lane & size) == 0;
        bool lower = (lane & stride) == 0;
        k = (lower == up) ? min(k, other) : max(k, other);
      }
    }
    if (lane < len) ew[beg + lane] = make_int2(k, __float_as_int(dinv[k] * dv));
  } else {
    for (unsigned e = beg + lane; e < end; e += 64) {
      int s = adj[e];
      ew[e] = make_int2(s, __float_as_int(dinv[s] * dv));
    }
  }
}
// all three weight transposes in one launch. W [K][N] fp32 -> Wt [Npad][K] bf16
__global__ void k_wt3(const float* __restrict__ W1, unsigned short* __restrict__ Wt1,
                      const float* __restrict__ W2, unsigned short* __restrict__ Wt2,
                      const float* __restrict__ W3, unsigned short* __restrict__ Wt3) {
  const int n1 = 256 * 1280, n2 = 256 * 256, n3 = 512 * 256;
  int idx = blockIdx.x * 256 + threadIdx.x;
  const float* W; unsigned short* Wt; int K, N;
  if (idx < n1)            { W = W1; Wt = Wt1; K = 1280; N = 256; }
  else if (idx < n1 + n2)  { W = W2; Wt = Wt2; K = 256;  N = 256; idx -= n1; }
  else if (idx < n1+n2+n3) { W = W3; Wt = Wt3; K = 256;  N = 500; idx -= n1 + n2; }
  else return;
  int nn = idx / K, k = idx - nn * K;
  float v = (nn < N) ? W[(size_t)k * N + nn] : 0.f;
  Wt[idx] = f2bf(v);
}

// ---------------- GEMM (bf16 A): C[M,N] = A[M,K] * Bt[N,K]^T ----------------
#define BM 128
#define BN 128
#define BK 64

template<int OUTF32>
__global__ __launch_bounds__(256, 4) void k_gemm(
    const unsigned short* __restrict__ Au, const unsigned short* __restrict__ Bt,
    void* __restrict__ Coutv, const float* __restrict__ bias,
    int M, int N, int K, int MT, int NT)
{
  __shared__ __align__(16) unsigned short As[BM * BK];
  __shared__ __align__(16) unsigned short Bs[BN * BK];

  int d = blockIdx.x;
  int xc = d & 7, sb = d >> 3;
  int nt = sb % NT, mt = (sb / NT) * 8 + xc;
  if (mt >= MT) return;
  int m0 = mt * BM, n0 = nt * BN;

  int tid = threadIdx.x, lane = tid & 63, wave = tid >> 6;
  int wm = wave >> 1, wn = wave & 1;
  int l15 = lane & 15, l4 = lane >> 4;

  f32x4 acc[4][4];
#pragma unroll
  for (int i = 0; i < 4; ++i)
#pragma unroll
    for (int j = 0; j < 4; ++j) acc[i][j] = 0.f;

  int srow[4], scg[4];
#pragma unroll
  for (int i = 0; i < 4; ++i) {
    int ci = (wave + 4 * i) * 64 + lane;
    srow[i] = ci >> 3;                         // 8 chunks per 128B row
    scg[i] = (ci & 7) ^ (srow[i] & 7);         // pre-swizzled source chunk
  }

  int nk = K / BK;
  for (int kt = 0; kt < nk; ++kt) {
    __syncthreads();
#pragma unroll
    for (int i = 0; i < 4; ++i) {
      int gr = m0 + srow[i]; gr = gr < M ? gr : M - 1;
      gld_lds16(Au + (size_t)gr * K + kt * BK + scg[i] * 8, As + (wave + 4 * i) * 512);
    }
#pragma unroll
    for (int i = 0; i < 4; ++i) {
      int gn = n0 + srow[i];
      gld_lds16(Bt + (size_t)gn * K + kt * BK + scg[i] * 8, Bs + (wave + 4 * i) * 512);
    }
    __syncthreads();

#pragma unroll
    for (int ks = 0; ks < 2; ++ks) {
      s16x8 af[4], bf[4];
#pragma unroll
      for (int f = 0; f < 4; ++f) {
        int r = wm * 64 + f * 16 + l15;
        int ca = (ks * 4 + l4) ^ (r & 7);
        af[f] = *(const s16x8*)(As + r * 64 + ca * 8);
        int nloc = wn * 64 + f * 16 + l15;
        int cb = (ks * 4 + l4) ^ (nloc & 7);
        bf[f] = *(const s16x8*)(Bs + nloc * 64 + cb * 8);
      }
#pragma unroll
      for (int fm = 0; fm < 4; ++fm)
#pragma unroll
        for (int fn = 0; fn < 4; ++fn)
          acc[fm][fn] = __builtin_amdgcn_mfma_f32_16x16x32_bf16(af[fm], bf[fn], acc[fm][fn], 0, 0, 0);
    }
  }

#pragma unroll
  for (int fm = 0; fm < 4; ++fm) {
#pragma unroll
    for (int fn = 0; fn < 4; ++fn) {
#pragma unroll
      for (int r = 0; r < 4; ++r) {
        int row = m0 + wm * 64 + fm * 16 + l4 * 4 + r;
        int col = n0 + wn * 64 + fn * 16 + l15;
        if (row < M && col < N) {
          if (OUTF32)
            ((float*)Coutv)[(size_t)row * N + col] = acc[fm][fn][r] + bias[col];
          else
            ((unsigned short*)Coutv)[(size_t)row * N + col] = f2bf(acc[fm][fn][r]);
        }
      }
    }
  }
}

// ------- GEMM variant: A is fp32 in global, staged fp32 via global_load_lds, cvt at frag read -------
__global__ __launch_bounds__(256, 3) void k_gemmF(
    const float* __restrict__ Af, const unsigned short* __restrict__ Bt,
    unsigned short* __restrict__ Cout, int M, int N, int K, int MT, int NT)
{
  __shared__ __align__(16) float As[BM * BK];           // 32 KB fp32
  __shared__ __align__(16) unsigned short Bs[BN * BK];  // 16 KB

  int d = blockIdx.x;
  int xc = d & 7, sb = d >> 3;
  int nt = sb % NT, mt = (sb / NT) * 8 + xc;
  if (mt >= MT) return;
  int m0 = mt * BM, n0 = nt * BN;

  int tid = threadIdx.x, lane = tid & 63, wave = tid >> 6;
  int wm = wave >> 1, wn = wave & 1;
  int l15 = lane & 15, l4 = lane >> 4;

  f32x4 acc[4][4];
#pragma unroll
  for (int i = 0; i < 4; ++i)
#pragma unroll
    for (int j = 0; j < 4; ++j) acc[i][j] = 0.f;

  // A: 2048 16B-chunks (16 chunks per 256B row), 8 per thread
  int arow[8], acs[8];
#pragma unroll
  for (int i = 0; i < 8; ++i) {
    int ci = (i * 4 + wave) * 64 + lane;
    arow[i] = ci >> 4;
    acs[i] = (ci & 15) ^ ((arow[i] & 7) << 1);  // pre-swizzled source chunk (pair-preserving)
  }
  // B: 1024 chunks (8 per 128B row), 4 per thread
  int brow[4], bcg[4];
#pragma unroll
  for (int i = 0; i < 4; ++i) {
    int ci = (i * 4 + wave) * 64 + lane;
    brow[i] = ci >> 3;
    bcg[i] = (ci & 7) ^ (brow[i] & 7);
  }

  int nk = K / BK;
  for (int kt = 0; kt < nk; ++kt) {
    __syncthreads();
#pragma unroll
    for (int i = 0; i < 8; ++i) {
      int gr = m0 + arow[i]; gr = gr < M ? gr : M - 1;
      gld_lds16(Af + (size_t)gr * K + kt * BK + acs[i] * 4, As + (i * 4 + wave) * 256);
    }
#pragma unroll
    for (int i = 0; i < 4; ++i) {
      int gn = n0 + brow[i];
      gld_lds16(Bt + (size_t)gn * K + kt * BK + bcg[i] * 8, Bs + (i * 4 + wave) * 512);
    }
    __syncthreads();

#pragma unroll
    for (int ks = 0; ks < 2; ++ks) {
      s16x8 af[4], bf[4];
#pragma unroll
      for (int f = 0; f < 4; ++f) {
        int r = wm * 64 + f * 16 + l15;
        int c0 = (2 * (ks * 4 + l4)) ^ ((r & 7) << 1);
        f32x4 a0 = *(const f32x4*)(As + r * 64 + c0 * 4);
        f32x4 a1 = *(const f32x4*)(As + r * 64 + c0 * 4 + 4);
        s16x8 pk;
        pk[0] = (short)f2bf(a0[0]); pk[1] = (short)f2bf(a0[1]);
        pk[2] = (short)f2bf(a0[2]); pk[3] = (short)f2bf(a0[3]);
        pk[4] = (short)f2bf(a1[0]); pk[5] = (short)f2bf(a1[1]);
        pk[6] = (short)f2bf(a1[2]); pk[7] = (short)f2bf(a1[3]);
        af[f] = pk;
        int nloc = wn * 64 + f * 16 + l15;
        int cb = (ks * 4 + l4) ^ (nloc & 7);
        bf[f] = *(const s16x8*)(Bs + nloc * 64 + cb * 8);
      }
#pragma unroll
      for (int fm = 0; fm < 4; ++fm)
#pragma unroll
        for (int fn = 0; fn < 4; ++fn)
          acc[fm][fn] = __builtin_amdgcn_mfma_f32_16x16x32_bf16(af[fm], bf[fn], acc[fm][fn], 0, 0, 0);
    }
  }

#pragma unroll
  for (int fm = 0; fm < 4; ++fm) {
#pragma unroll
    for (int fn = 0; fn < 4; ++fn) {
#pragma unroll
      for (int r = 0; r < 4; ++r) {
        int row = m0 + wm * 64 + fm * 16 + l4 * 4 + r;
        int col = n0 + wn * 64 + fn * 16 + l15;
        if (row < M && col < N)
          Cout[(size_t)row * N + col] = f2bf(acc[fm][fn][r]);
      }
    }
  }
}

// -------- aggregation (C=256), 16-deep pipelined row gathers --------
__device__ __forceinline__ void accum4(float& a0, float& a1, float& a2, float& a3,
                                       u16x4 q, float w) {
  a0 += bf2f(q[0]) * w; a1 += bf2f(q[1]) * w;
  a2 += bf2f(q[2]) * w; a3 += bf2f(q[3]) * w;
}

template<int BNRELU, int BIAS>
__global__ __launch_bounds__(256) void k_agg(
    const unsigned short* __restrict__ h, const int2* __restrict__ ew,
    const unsigned* __restrict__ offs, const float* __restrict__ bias,
    const float* __restrict__ gam, const float* __restrict__ bet,
    const float* __restrict__ mea, const float* __restrict__ var,
    unsigned short* __restrict__ outp, int nN)
{
  const int C = 256;
  int wave = threadIdx.x >> 6, lane = threadIdx.x & 63;
  int v = blockIdx.x * 4 + wave;
  if (v >= nN) return;
  unsigned beg = offs[v], end = offs[v + 1];
  int len = (int)(end - beg);
  int ch0 = lane * 4;
  const unsigned short* hb = h + ch0;
  float a0 = 0, a1 = 0, a2 = 0, a3 = 0;

  for (int base = 0; base < len; base += 64) {
    int m = min(64, len - base);
    int2 myp = make_int2(0, 0);               // pads: src 0, weight 0
    if (lane < m) myp = ew[beg + base + lane];
    int ng = (m + 15) >> 4;

    u16x4 q[16];
#pragma unroll
    for (int r = 0; r < 16; ++r) {
      int s = __shfl(myp.x, r);
      q[r] = *(const u16x4*)(hb + (size_t)s * C);
    }
    for (int g = 1; g < ng; ++g) {
      u16x4 q2[16];
#pragma unroll
      for (int r = 0; r < 16; ++r) {
        int s = __shfl(myp.x, g * 16 + r);
        q2[r] = *(const u16x4*)(hb + (size_t)s * C);
      }
#pragma unroll
      for (int r = 0; r < 16; ++r) {
        float w = __int_as_float(__shfl(myp.y, (g - 1) * 16 + r));
        accum4(a0, a1, a2, a3, q[r], w);
      }
#pragma unroll
      for (int r = 0; r < 16; ++r) q[r] = q2[r];
    }
#pragma unroll
    for (int r = 0; r < 16; ++r) {
      float w = __int_as_float(__shfl(myp.y, (ng - 1) * 16 + r));
      accum4(a0, a1, a2, a3, q[r], w);
    }
  }

  float va[4] = {a0, a1, a2, a3};
#pragma unroll
  for (int j = 0; j < 4; ++j) {
    int ch = ch0 + j;
    float val = va[j];
    if (BIAS) val += bias[ch];
    if (BNRELU) {
      val = (val - mea[ch]) * rsqrtf(var[ch] + EPSBN) * gam[ch] + bet[ch];
      val = fmaxf(val, 0.f);
    }
    outp[(size_t)v * C + ch] = f2bf(val);
  }
}

// ---------------- launch ----------------
extern "C" void kernel_launch(void* const* d_in, const int* in_sizes, int n_in,
                              void* d_out, int out_size, void* d_ws, size_t ws_size,
                              hipStream_t stream) {
  const float* x   = (const float*)d_in[0];
  const int*   ei  = (const int*)d_in[1];
  const float* W1  = (const float*)d_in[2];
  const float* b1  = (const float*)d_in[3];
  const float* g1  = (const float*)d_in[4];
  const float* be1 = (const float*)d_in[5];
  const float* m1  = (const float*)d_in[6];
  const float* v1  = (const float*)d_in[7];
  const float* W2  = (const float*)d_in[8];
  const float* b2  = (const float*)d_in[9];
  const float* g2  = (const float*)d_in[10];
  const float* be2 = (const float*)d_in[11];
  const float* m2  = (const float*)d_in[12];
  const float* v2  = (const float*)d_in[13];
  const float* W3  = (const float*)d_in[14];
  const float* b3  = (const float*)d_in[15];

  const int IN = 1280, H = 256, OUT = 500, OUTP = 512;
  int E  = in_sizes[1] / 2;
  int nN = in_sizes[0] / IN;
  const int* srcI = ei;
  const int* dstI = ei + E;

  char* p = (char*)d_ws;
  auto carve = [&](size_t bytes) { char* r = p; p += (bytes + 511) & ~(size_t)511; return r; };
  unsigned short* Wt1 = (unsigned short*)carve((size_t)H * IN * 2);
  unsigned short* Wt2 = (unsigned short*)carve((size_t)H * H * 2);
  unsigned short* Wt3 = (unsigned short*)carve((size_t)OUTP * H * 2);
  unsigned* deg  = (unsigned*)carve((size_t)nN * 4);
  float*    dinv = (float*)carve((size_t)nN * 4);
  unsigned* offs = (unsigned*)carve((size_t)(nN + 1) * 4);
  unsigned* cur  = (unsigned*)carve((size_t)nN * 4);
  unsigned* bsum = (unsigned*)carve(256 * 4);
  unsigned* bpre = (unsigned*)carve(256 * 4);
  int*      adj  = (int*)carve((size_t)(E + nN) * 4);
  int2*     ew   = (int2*)carve((size_t)(E + nN) * 8);
  unsigned short* bufA = (unsigned short*)carve((size_t)nN * H * 2);  // pre-agg h
  unsigned short* bufB = (unsigned short*)carve((size_t)nN * H * 2);  // post-agg act

  int NB = (nN + 255) / 256;
  k_init_deg<<<NB, 256, 0, stream>>>(deg, nN);
  k_count<<<(E + 255) / 256, 256, 0, stream>>>(dstI, deg, E);
  k_prep2<<<NB, 256, 0, stream>>>(deg, dinv, bsum, nN);
  k_scan_top<<<1, 256, 0, stream>>>(bsum, bpre, NB, offs, nN);
  k_scan_fin<<<NB, 256, 0, stream>>>(deg, bpre, offs, cur, nN);
  k_fill<<<(E + nN + 255) / 256, 256, 0, stream>>>(srcI, dstI, cur, adj, E, nN);
  k_sortw<<<(nN + 3) / 4, 256, 0, stream>>>(offs, adj, dinv, ew, nN);
  k_wt3<<<(H * IN + H * H + OUTP * H + 255) / 256, 256, 0, stream>>>(W1, Wt1, W2, Wt2, W3, Wt3);

  int MT = (nN + BM - 1) / BM;          // 391
  int mg = (MT + 7) / 8;                // 49
  int nAgg = (nN + 3) / 4;

  // layer 1:  h1 = x*W1 ; act1 = BNReLU(agg(h1)+b1)
  k_gemmF<<<mg * 8 * 2, 256, 0, stream>>>(x, Wt1, bufA, nN, H, IN, MT, 2);
  k_agg<1, 1><<<nAgg, 256, 0, stream>>>(bufA, ew, offs, b1, g1, be1, m1, v1, bufB, nN);
  // layer 2:  h2 = act1*W2 ; act2 = BNReLU(agg(h2)+b2)
  k_gemm<0><<<mg * 8 * 2, 256, 0, stream>>>(bufB, Wt2, bufA, nullptr, nN, H, H, MT, 2);
  k_agg<1, 1><<<nAgg, 256, 0, stream>>>(bufA, ew, offs, b2, g2, be2, m2, v2, bufB, nN);
  // layer 3 (reordered):  out = (agg(act2)) * W3 + b3
  k_agg<0, 0><<<nAgg, 256, 0, stream>>>(bufB, ew, offs, nullptr, nullptr, nullptr, nullptr, nullptr, bufA, nN);
  k_gemm<1><<<mg * 8 * 4, 256, 0, stream>>>(bufA, Wt3, d_out, b3, nN, OUT, H, MT, 4);
}